// Round 6
// baseline (248.163 us; speedup 1.0000x reference)
//
#include <hip/hip_runtime.h>
#include <hip/hip_bf16.h>
#include <stdint.h>

#define N_ROWS 16384

typedef __bf16 bf16x8 __attribute__((ext_vector_type(8)));
typedef float f32x4 __attribute__((ext_vector_type(4)));

#define AS1 __attribute__((address_space(1)))
#define AS3 __attribute__((address_space(3)))

// ---------------- ws layout (bytes) ----------------
// WcS : (W_token@W_qkv)^T bf16 [384][768], 8-elt chunks XOR-swizzled   589824
// bc  : f32 [384]  (b_token@W_qkv + b_qkv)                               1536
// qb  : bf16 [16384][128]  (q * -log2e)                               4194304
// kb  : bf16 [16384][128]  (plain row-major)                          4194304
// wv  : f32  [16384]  ((v+bias) . W_fc)                                 65536
#define OFF_WCS  0u
#define OFF_BC   589824u
#define OFF_QB   591360u
#define OFF_KB   4785664u
#define OFF_WV   8979968u

// ---- kernel 0: Wc = W_token @ W_qkv -> bf16, [n][768] with 8-elt chunk XOR swizzle;
//      bc = b_token @ W_qkv + b_qkv ----
__global__ void prep(const float* __restrict__ Wt, const float* __restrict__ Wq,
                     const float* __restrict__ bt, const float* __restrict__ bq,
                     __bf16* __restrict__ WcS, float* __restrict__ bc) {
    int u = blockIdx.x * 256 + threadIdx.x;          // [0, 768*96)
    if (u < 768 * 96) {
        int k = u / 96, n4 = u % 96;
        float s[4] = {0, 0, 0, 0};
        const float* wtp = Wt + k * 128;
        const float* wqp = Wq + n4 * 4;
#pragma unroll 8
        for (int d = 0; d < 128; d++) {
            float a = wtp[d];
            float4 b = *(const float4*)(wqp + d * 384);
            s[0] += a * b.x; s[1] += a * b.y; s[2] += a * b.z; s[3] += a * b.w;
        }
        int kb_ = k >> 6, c = (k >> 3) & 7, k7 = k & 7;
#pragma unroll
        for (int j = 0; j < 4; j++) {
            int n = n4 * 4 + j;
            WcS[n * 768 + kb_ * 64 + ((c ^ (n & 7)) << 3) + k7] = (__bf16)s[j];
        }
    }
    if (u < 384) {
        float s = bq[u];
        for (int d = 0; d < 128; d++) s += bt[d] * Wq[d * 384 + u];
        bc[u] = s;
    }
}

// ---- kernel 1: qkv = bf16(x) @ Wc + bc via LDS-staged tiled GEMM ----
// BM=64, BN=128, BK=64; grid (256, 3); sp aligns with q / k / v+wv epilogues.
// sp==2 blocks also initialize out[row] = b_fc (attn atomically accumulates later).
__launch_bounds__(256)
__global__ void gemm_qkv(const float* __restrict__ x, const __bf16* __restrict__ WcS,
                         const float* __restrict__ bc, const float* __restrict__ W_fc,
                         const float* __restrict__ b_fc,
                         __bf16* __restrict__ qb, __bf16* __restrict__ kb,
                         float* __restrict__ wv, float* __restrict__ out) {
    __shared__ float  Asm_[64 * 64];   // fp32 A tile, 16B-chunk XOR-swizzled
    __shared__ __bf16 Bsm[128 * 64];   // bf16 B tile, 16B-chunk XOR-swizzled
    __shared__ float  wred[64];
    const int tid = threadIdx.x, wave = tid >> 6, lane = tid & 63;
    const int n16 = lane & 15, q = lane >> 4;
    const int mh = wave >> 1, nw = wave & 1;
    const int row0 = blockIdx.x * 64;
    const int sp = blockIdx.y;

    if (sp == 2 && tid < 64) out[row0 + tid] = b_fc[0];

    // per-lane staging source pointers (swizzle baked into the global address)
    const char* aptr[4];
    const char* bptr[4];
    {
        int p = (lane & 15) >> 1, half = lane & 1;
#pragma unroll
        for (int i = 0; i < 4; i++) {
            int ar = row0 + wave * 16 + i * 4 + (lane >> 4);
            aptr[i] = (const char*)x + (size_t)ar * 3072 + ((p ^ (ar & 7)) * 8 + half * 4) * 4;
            int br = sp * 128 + wave * 32 + i * 8 + (lane >> 3);
            bptr[i] = (const char*)WcS + (size_t)br * 1536 + (lane & 7) * 16;
        }
    }
    f32x4 acc[2][4];
#pragma unroll
    for (int mt = 0; mt < 2; mt++)
#pragma unroll
        for (int t = 0; t < 4; t++) acc[mt][t] = (f32x4){0, 0, 0, 0};

    for (int kbi = 0; kbi < 12; kbi++) {
#pragma unroll
        for (int i = 0; i < 4; i++)
            __builtin_amdgcn_global_load_lds((const AS1 void*)(aptr[i] + kbi * 256),
                (AS3 void*)((char*)Asm_ + wave * 4096 + i * 1024), 16, 0, 0);
#pragma unroll
        for (int i = 0; i < 4; i++)
            __builtin_amdgcn_global_load_lds((const AS1 void*)(bptr[i] + kbi * 128),
                (AS3 void*)((char*)Bsm + wave * 4096 + i * 1024), 16, 0, 0);
        __syncthreads();
#pragma unroll
        for (int ks = 0; ks < 2; ks++) {
            const int P = ks * 4 + q;
            bf16x8 af[2];
#pragma unroll
            for (int mt = 0; mt < 2; mt++) {
                const int r = mh * 32 + mt * 16 + n16;
                const int sa = r & 7;
                // store side put x[r][ (p^sa)*8 + half*4 .. +4 ] at float pos p*8+half*4,
                // so cols P*8..P*8+7 live at float pos (P^sa)*8 .. +8 (halves in order).
                const float* ap = Asm_ + r * 64 + ((P ^ sa) << 3);
                f32x4 f0 = *(const f32x4*)ap;
                f32x4 f1 = *(const f32x4*)(ap + 4);
                bf16x8 t;
                t[0] = (__bf16)f0[0]; t[1] = (__bf16)f0[1]; t[2] = (__bf16)f0[2]; t[3] = (__bf16)f0[3];
                t[4] = (__bf16)f1[0]; t[5] = (__bf16)f1[1]; t[6] = (__bf16)f1[2]; t[7] = (__bf16)f1[3];
                af[mt] = t;
            }
#pragma unroll
            for (int t = 0; t < 4; t++) {
                const int swz = (P ^ (n16 & 7)) << 3;
                bf16x8 bf = *(const bf16x8*)(Bsm + (nw * 64 + t * 16 + n16) * 64 + swz);
                acc[0][t] = __builtin_amdgcn_mfma_f32_16x16x32_bf16(af[0], bf, acc[0][t], 0, 0, 0);
                acc[1][t] = __builtin_amdgcn_mfma_f32_16x16x32_bf16(af[1], bf, acc[1][t], 0, 0, 0);
            }
        }
        __syncthreads();
    }

    // epilogue: cols of this block = sp*128 + nw*64 + t*16 + n16
    const int clb = nw * 64 + n16;
    if (sp == 0) {
#pragma unroll
        for (int t = 0; t < 4; t++) {
            int cl = clb + t * 16;
            float bcv = bc[cl];
#pragma unroll
            for (int mt = 0; mt < 2; mt++)
#pragma unroll
                for (int r = 0; r < 4; r++) {
                    int row = row0 + mh * 32 + mt * 16 + q * 4 + r;
                    qb[row * 128 + cl] = (__bf16)((acc[mt][t][r] + bcv) * -1.44269504088896f);
                }
        }
    } else if (sp == 1) {
#pragma unroll
        for (int t = 0; t < 4; t++) {
            int d = clb + t * 16;
            float bcv = bc[128 + d];
#pragma unroll
            for (int mt = 0; mt < 2; mt++)
#pragma unroll
                for (int r = 0; r < 4; r++) {
                    int row = row0 + mh * 32 + mt * 16 + q * 4 + r;
                    kb[row * 128 + d] = (__bf16)(acc[mt][t][r] + bcv);
                }
        }
    } else {
        float wacc[2][4] = {{0, 0, 0, 0}, {0, 0, 0, 0}};
#pragma unroll
        for (int t = 0; t < 4; t++) {
            int cl = clb + t * 16;
            float bcv = bc[256 + cl];
            float wf = W_fc[cl];
#pragma unroll
            for (int mt = 0; mt < 2; mt++)
#pragma unroll
                for (int r = 0; r < 4; r++) wacc[mt][r] += (acc[mt][t][r] + bcv) * wf;
        }
        float vred[2][4];
#pragma unroll
        for (int mt = 0; mt < 2; mt++)
#pragma unroll
            for (int r = 0; r < 4; r++) {
                float v = wacc[mt][r];
                v += __shfl_xor(v, 1, 64);
                v += __shfl_xor(v, 2, 64);
                v += __shfl_xor(v, 4, 64);
                v += __shfl_xor(v, 8, 64);
                vred[mt][r] = v;
                if (nw == 0 && n16 == 0) wred[mh * 32 + mt * 16 + q * 4 + r] = v;
            }
        __syncthreads();
        if (nw == 1 && n16 == 0) {
#pragma unroll
            for (int mt = 0; mt < 2; mt++)
#pragma unroll
                for (int r = 0; r < 4; r++) {
                    int lr = mh * 32 + mt * 16 + q * 4 + r;
                    wv[row0 + lr] = wred[lr] + vred[mt][r];
                }
        }
    }
}

// ---- kernel 2: out[i] += sum_{j in slice} sigmoid(q_i.k_j) * wv_j ----
// Barrier-free streaming: B-frags read directly from L2-resident kb with
// distance-1 register prefetch. 256 threads = 4 waves x 64 rows; 16 j-slices.
__launch_bounds__(256, 3)
__global__ void attn(const __bf16* __restrict__ qb, const __bf16* __restrict__ kb,
                     const float* __restrict__ wv, float* __restrict__ out) {
    const int tid = threadIdx.x;
    const int wave = tid >> 6, lane = tid & 63;
    const int n16 = lane & 15, q = lane >> 4;
    const int row0 = blockIdx.x * 256 + wave * 64;
    const int jbase = blockIdx.y * 1024;

    bf16x8 qf[4][4];
#pragma unroll
    for (int mt = 0; mt < 4; mt++)
#pragma unroll
        for (int ks = 0; ks < 4; ks++)
            qf[mt][ks] = *(const bf16x8*)(qb + (row0 + mt * 16 + n16) * 128 + ks * 32 + q * 8);

    float acc[4][4] = {{0}, {0}, {0}, {0}};
    const __bf16* kp = kb + (size_t)(jbase + n16) * 128 + q * 8;  // j-row = jbase+st*16+n16
    const float* wp = wv + jbase + n16;

    bf16x8 bcur[4];
    float wcur;
#pragma unroll
    for (int ks = 0; ks < 4; ks++) bcur[ks] = *(const bf16x8*)(kp + ks * 32);
    wcur = wp[0];

#pragma unroll 2
    for (int st = 0; st < 64; st++) {
        // prefetch step st+1 (last iter reads past kb end -> lands in wv, unused)
        bf16x8 bnxt[4];
        const __bf16* kpn = kp + (size_t)(st + 1) * 2048;
#pragma unroll
        for (int ks = 0; ks < 4; ks++) bnxt[ks] = *(const bf16x8*)(kpn + ks * 32);
        float wnxt = wp[(st + 1) * 16];

        f32x4 sc[4];
#pragma unroll
        for (int mt = 0; mt < 4; mt++) sc[mt] = (f32x4){0, 0, 0, 0};
#pragma unroll
        for (int ks = 0; ks < 4; ks++)
#pragma unroll
            for (int mt = 0; mt < 4; mt++)
                sc[mt] = __builtin_amdgcn_mfma_f32_16x16x32_bf16(qf[mt][ks], bcur[ks], sc[mt], 0, 0, 0);
#pragma unroll
        for (int mt = 0; mt < 4; mt++)
#pragma unroll
            for (int r = 0; r < 4; r++)
                // qb pre-scaled by -log2e: sigmoid(s) = rcp(1 + exp2(s'))
                acc[mt][r] += __builtin_amdgcn_rcpf(1.0f + __builtin_amdgcn_exp2f(sc[mt][r])) * wcur;
#pragma unroll
        for (int ks = 0; ks < 4; ks++) bcur[ks] = bnxt[ks];
        wcur = wnxt;
    }

#pragma unroll
    for (int mt = 0; mt < 4; mt++)
#pragma unroll
        for (int r = 0; r < 4; r++) {
            float v = acc[mt][r];
            v += __shfl_xor(v, 1, 64);
            v += __shfl_xor(v, 2, 64);
            v += __shfl_xor(v, 4, 64);
            v += __shfl_xor(v, 8, 64);
            if (n16 == 0) atomicAdd(&out[row0 + mt * 16 + q * 4 + r], v);
        }
}

extern "C" void kernel_launch(void* const* d_in, const int* in_sizes, int n_in,
                              void* d_out, int out_size, void* d_ws, size_t ws_size,
                              hipStream_t stream) {
    const float* x       = (const float*)d_in[0];
    // d_in[1] = decay_value (unused by reference)
    const float* W_token = (const float*)d_in[2];
    const float* b_token = (const float*)d_in[3];
    const float* W_qkv   = (const float*)d_in[4];
    const float* b_qkv   = (const float*)d_in[5];
    const float* W_fc    = (const float*)d_in[6];
    const float* b_fc    = (const float*)d_in[7];
    float* out = (float*)d_out;
    char* ws = (char*)d_ws;

    __bf16* WcS = (__bf16*)(ws + OFF_WCS);
    float*  bc  = (float*)(ws + OFF_BC);
    __bf16* qb  = (__bf16*)(ws + OFF_QB);
    __bf16* kb  = (__bf16*)(ws + OFF_KB);
    float*  wv  = (float*)(ws + OFF_WV);

    prep<<<288, 256, 0, stream>>>(W_token, W_qkv, b_token, b_qkv, WcS, bc);
    gemm_qkv<<<dim3(256, 3), 256, 0, stream>>>(x, WcS, bc, W_fc, b_fc, qb, kb, wv, out);
    attn<<<dim3(64, 16), 256, 0, stream>>>(qb, kb, wv, out);
}